// Round 13
// baseline (133.238 us; speedup 1.0000x reference)
//
#include <hip/hip_runtime.h>
#include <stdint.h>

#define LATENT 10
#define MAXLEN 80
#define STEPS  10
#define HIDDEN 32
#define BATCH  512
#define NSEG   16
#define SEGL   5       // MAXLEN / NSEG
#define CPB    16      // chains per block
#define TPB    128     // threads per block (2 waves, all productive)

typedef float v2f __attribute__((ext_vector_type(2)));

// ---------------------------------------------------------------------------
// Threefry-2x32, 20 rounds — bit-exact replica of jax threefry2x32_p.
// ---------------------------------------------------------------------------
__device__ __forceinline__ void tf2x32(uint32_t k0, uint32_t k1,
                                       uint32_t x0, uint32_t x1,
                                       uint32_t& o0, uint32_t& o1) {
  uint32_t ks2 = k0 ^ k1 ^ 0x1BD11BDAu;
  uint32_t v0 = x0 + k0;
  uint32_t v1 = x1 + k1;
#define TF_R(rot) { v0 += v1; v1 = (v1 << (rot)) | (v1 >> (32 - (rot))); v1 ^= v0; }
  TF_R(13) TF_R(15) TF_R(26) TF_R(6)
  v0 += k1;  v1 += ks2 + 1u;
  TF_R(17) TF_R(29) TF_R(16) TF_R(24)
  v0 += ks2; v1 += k0 + 2u;
  TF_R(13) TF_R(15) TF_R(26) TF_R(6)
  v0 += k0;  v1 += k1 + 3u;
  TF_R(17) TF_R(29) TF_R(16) TF_R(24)
  v0 += k1;  v1 += ks2 + 4u;
  TF_R(13) TF_R(15) TF_R(26) TF_R(6)
  v0 += ks2; v1 += k0 + 5u;
#undef TF_R
  o0 = v0; o1 = v1;
}

// JAX uniform(-0.99999994, 1) bits -> sqrt(2)*erfinv(u).
// XLA Giles polynomial; w via fast hw log (1-ulp class, threshold has 10x margin).
__device__ __forceinline__ float bits_to_normal(uint32_t bits) {
  const float lo = -0.99999994f;                                 // nextafter(-1, 0)
  float f = __uint_as_float((bits >> 9) | 0x3f800000u) - 1.0f;   // [0,1)
  float u = fmaf(f, 2.0f, lo);                                   // (hi-lo) rounds to 2.0f
  u = fmaxf(u, lo);
  float w = -__logf(fmaf(-u, u, 1.0f));                          // -ln(1-u^2)
  float p;
  if (w < 5.0f) {
    w -= 2.5f;
    p = 2.81022636e-08f;
    p = fmaf(p, w, 3.43273939e-07f);
    p = fmaf(p, w, -3.5233877e-06f);
    p = fmaf(p, w, -4.39150654e-06f);
    p = fmaf(p, w, 0.00021858087f);
    p = fmaf(p, w, -0.00125372503f);
    p = fmaf(p, w, -0.00417768164f);
    p = fmaf(p, w, 0.246640727f);
    p = fmaf(p, w, 1.50140941f);
  } else {
    w = sqrtf(w) - 3.0f;
    p = -0.000200214257f;
    p = fmaf(p, w, 0.000100950558f);
    p = fmaf(p, w, 0.00134934322f);
    p = fmaf(p, w, -0.00367342844f);
    p = fmaf(p, w, 0.00573950773f);
    p = fmaf(p, w, -0.0076224613f);
    p = fmaf(p, w, 0.00943887047f);
    p = fmaf(p, w, 1.00167406f);
    p = fmaf(p, w, 2.83297682f);
  }
  return 1.4142135623730951f * (p * u);
}

// ---------------------------------------------------------------------------
// Kernel 1: segment totals. segtot[s][b][j] = sum_{l in seg s} mu[b,l,:].W1[.,j]
// Packed accumulator: acc.x = even-d partial, acc.y = odd-d partial.
// ---------------------------------------------------------------------------
__global__ __launch_bounds__(256) void k_seg(
    const float* __restrict__ zmean, const float* __restrict__ W1,
    float* __restrict__ segtot) {
  int id = blockIdx.x * 256 + threadIdx.x;    // 0..262143
  int s = id >> 14;                           // segment, block-uniform
  int r = id & 16383;
  int b = r >> 5, j = r & 31;
  v2f acc = {0.0f, 0.0f};
#pragma unroll
  for (int t = 0; t < SEGL; ++t) {
    int l = s * SEGL + t;
    const float2* mrow = (const float2*)(zmean + (b * MAXLEN + l) * LATENT);
    const float* wl = W1 + (l * LATENT) * HIDDEN + j;
#pragma unroll
    for (int p = 0; p < 5; ++p) {
      float2 m = mrow[p];
      v2f mm = {m.x, m.y};
      v2f ww = {wl[(2 * p) * HIDDEN], wl[(2 * p + 1) * HIDDEN]};
      acc = mm * ww + acc;                    // v_pk_fma_f32 (ffp-contract)
    }
  }
  segtot[(s * BATCH + b) * HIDDEN + j] = acc.x + acc.y;
}

// ---------------------------------------------------------------------------
// Kernel 2: block = (i, 16 b's), 128 threads (2 waves), 2560 blocks — whole
// grid co-resident. NO min-waves hint (R11: reg-cap -> 500 MB spill, 3.7x).
// Phase A: 11 subkeys -> LDS. Phase B: 1760 normals -> LDS (13 full rounds +
// 96-thread tail), dW draws pre-scaled by sqrt(dt). Phase C: 8 lanes/chain,
// latent math packed as float2 pairs -> v_pk_fma_f32 (full-rate dual fp32).
// ---------------------------------------------------------------------------
__global__ __launch_bounds__(TPB) void k_chain(
    const float* __restrict__ zmean, const float* __restrict__ zlv,
    const float* __restrict__ W1, const float* __restrict__ b1v,
    const float* __restrict__ W2, const float* __restrict__ b2v,
    const float* __restrict__ segtot,
    float* __restrict__ outSeq, float* __restrict__ outErr) {
  __shared__ float nrmS[(STEPS + 1) * LATENT * CPB];  // 7040 B
  __shared__ uint32_t skk[2 * (STEPS + 1)];

  const int tid = threadIdx.x;
  const int i = blockIdx.x >> 5;                      // block-uniform
  const int b0 = (blockIdx.x & 31) << 4;

  // ---- phase A: 11 subkeys for this i ----
  if (tid < (STEPS + 1)) {
    uint32_t a, c;
    tf2x32(0u, 1337u, 0u, (uint32_t)(i * (STEPS + 1) + tid), a, c);
    skk[2 * tid] = a; skk[2 * tid + 1] = c;
  }
  __syncthreads();

  // ---- phase B: 1760 normals (13 full rounds + 96-thread tail) ----
  const float SQRT_DT = 0.31622776601683794f;
#define GEN_DRAW(IDX)                                                        \
  {                                                                          \
    int c_ = (IDX) & (CPB - 1), n_ = (IDX) >> 4;                             \
    int k_ = (n_ * 205) >> 11;                                               \
    int d_ = n_ - k_ * 10;                                                   \
    uint32_t o0_, o1_;                                                       \
    tf2x32(skk[2 * k_], skk[2 * k_ + 1], 0u,                                 \
           (uint32_t)((b0 + c_) * LATENT + d_), o0_, o1_);                   \
    float v_ = bits_to_normal(o0_ ^ o1_);                                    \
    nrmS[n_ * CPB + c_] = (n_ < LATENT) ? v_ : v_ * SQRT_DT;                 \
  }
#pragma unroll
  for (int rr = 0; rr < 13; ++rr) GEN_DRAW(rr * TPB + tid);
  if (tid < (STEPS + 1) * LATENT * CPB - 13 * TPB) GEN_DRAW(13 * TPB + tid);
#undef GEN_DRAW
  __syncthreads();

  // ---- phase C: all 128 threads = 16 chains x 8 lanes ----
  const int r = tid & 7;                              // lane-in-chain
  const int jb = r * 4;                               // first hidden unit
  const int cloc = tid >> 3;                          // chain-in-block
  const int b = b0 + cloc;

  // base hidden pre-activation: pf = b1 + i*wT + prefix(segments + partials)
  const float* rowT = W1 + (MAXLEN * LATENT) * HIDDEN;
  v2f pf2[2], wT2[2];
  {
    float4 wt4 = *(const float4*)(rowT + jb);
    float4 b14 = *(const float4*)(b1v + jb);
    wT2[0] = (v2f){wt4.x, wt4.y}; wT2[1] = (v2f){wt4.z, wt4.w};
    const float fi = (float)i;
    pf2[0] = fi * wT2[0] + (v2f){b14.x, b14.y};
    pf2[1] = fi * wT2[1] + (v2f){b14.z, b14.w};
  }
  const int fs = i / SEGL;                            // full segments (uniform)
  for (int s2 = 0; s2 < fs; ++s2) {
    float4 t0 = *(const float4*)(segtot + ((size_t)s2 * BATCH + b) * HIDDEN + jb);
    pf2[0] += (v2f){t0.x, t0.y};
    pf2[1] += (v2f){t0.z, t0.w};
  }
  for (int l = fs * SEGL; l < i; ++l) {               // <= 4 partial l's
    const float2* mrow = (const float2*)(zmean + (b * MAXLEN + l) * LATENT);
    const float* wl = W1 + (l * LATENT) * HIDDEN + jb;
#pragma unroll
    for (int p = 0; p < 5; ++p) {
      float2 m = mrow[p];
      float4 wa = *(const float4*)(wl + (2 * p) * HIDDEN);
      float4 wb = *(const float4*)(wl + (2 * p + 1) * HIDDEN);
      pf2[0] = m.x * (v2f){wa.x, wa.y} + pf2[0];
      pf2[1] = m.x * (v2f){wa.z, wa.w} + pf2[1];
      pf2[0] = m.y * (v2f){wb.x, wb.y} + pf2[0];
      pf2[1] = m.y * (v2f){wb.z, wb.w} + pf2[1];
    }
  }

  // per-chain latent params; fold mu into pf, sstd into W1 lane slice
  const int base = (b * MAXLEN + i) * LATENT;
  v2f mu2[5], shalf2[5], u2[5], errs2[5], b22[5];
  v2f w1s2[LATENT][2];
  {
    const float2* zm = (const float2*)(zmean + base);
    const float2* zl = (const float2*)(zlv + base);
    const float2* b2p = (const float2*)b2v;
    const float* W1i = W1 + (i * LATENT) * HIDDEN + jb;
#pragma unroll
    for (int p = 0; p < 5; ++p) {
      float2 m = zm[p], v = zl[p];
      float s0 = sqrtf(expf(v.x));
      float s1 = sqrtf(expf(v.y));
      mu2[p] = (v2f){m.x, m.y};
      shalf2[p] = (v2f){0.5f * s0, 0.5f * s1};
      float2 bb = b2p[p];
      b22[p] = (v2f){bb.x, bb.y};
      errs2[p] = (v2f){0.0f, 0.0f};
      float4 wa = *(const float4*)(W1i + (2 * p) * HIDDEN);
      float4 wb = *(const float4*)(W1i + (2 * p + 1) * HIDDEN);
      // pf += mu_d * w1_d (step-invariant part of xt = mu + sstd*u)
      pf2[0] = m.x * (v2f){wa.x, wa.y} + pf2[0];
      pf2[1] = m.x * (v2f){wa.z, wa.w} + pf2[1];
      pf2[0] = m.y * (v2f){wb.x, wb.y} + pf2[0];
      pf2[1] = m.y * (v2f){wb.z, wb.w} + pf2[1];
      // scaled weights: w1s[d] = sstd_d * w1[d][jb..jb+3]
      w1s2[2 * p][0] = s0 * (v2f){wa.x, wa.y};
      w1s2[2 * p][1] = s0 * (v2f){wa.z, wa.w};
      w1s2[2 * p + 1][0] = s1 * (v2f){wb.x, wb.y};
      w1s2[2 * p + 1][1] = s1 * (v2f){wb.z, wb.w};
    }
  }
#pragma unroll
  for (int p = 0; p < 5; ++p)                         // k = 0 draw: u0 = n0
    u2[p] = (v2f){nrmS[(2 * p) * CPB + cloc], nrmS[(2 * p + 1) * CPB + cloc]};

  const float* W2q = W2 + jb * LATENT;

  for (int s = 0; s < STEPS; ++s) {
    // this step's noise (k = s+1), pre-scaled by sqrt(dt); bank-broadcast reads
    v2f nd2[5];
#pragma unroll
    for (int p = 0; p < 5; ++p)
      nd2[p] = (v2f){nrmS[((s + 1) * LATENT + 2 * p) * CPB + cloc],
                     nrmS[((s + 1) * LATENT + 2 * p + 1) * CPB + cloc]};

    const float ts = (float)s * 0.1f;
    v2f h2[2];
    h2[0] = ts * wT2[0] + pf2[0];
    h2[1] = ts * wT2[1] + pf2[1];
#pragma unroll
    for (int p = 0; p < 5; ++p) {
      float ua = u2[p].x, ub = u2[p].y;
      h2[0] = ua * w1s2[2 * p][0] + h2[0];
      h2[1] = ua * w1s2[2 * p][1] + h2[1];
      h2[0] = ub * w1s2[2 * p + 1][0] + h2[0];
      h2[1] = ub * w1s2[2 * p + 1][1] + h2[1];
    }
    float hj[4] = {fmaxf(h2[0].x, 0.0f), fmaxf(h2[0].y, 0.0f),
                   fmaxf(h2[1].x, 0.0f), fmaxf(h2[1].y, 0.0f)};
    // partial score over this lane's 4 hidden units
    v2f sc2[5];
#pragma unroll
    for (int p = 0; p < 5; ++p) sc2[p] = (v2f){0.0f, 0.0f};
#pragma unroll
    for (int k = 0; k < 4; ++k) {
      const v2f* w2r = (const v2f*)(W2q + k * LATENT);  // 8B-aligned
      const float hk = hj[k];
#pragma unroll
      for (int p = 0; p < 5; ++p) sc2[p] = hk * w2r[p] + sc2[p];
    }
    // reduce across the 8 lanes of the chain
#pragma unroll
    for (int m = 1; m < 8; m <<= 1) {
#pragma unroll
      for (int p = 0; p < 5; ++p) {
        float ox = __shfl_xor(sc2[p].x, m);
        float oy = __shfl_xor(sc2[p].y, m);
        sc2[p] += (v2f){ox, oy};
      }
    }
    // update: u += shalf*st + nd ; err += |u + st|
#pragma unroll
    for (int p = 0; p < 5; ++p) {
      v2f st = sc2[p] + b22[p];
      v2f t = u2[p] + st;                              // -(logdx - st)
      errs2[p] += (v2f){fabsf(t.x), fabsf(t.y)};
      u2[p] = u2[p] + (shalf2[p] * st + nd2[p]);
    }
  }

  // ---- epilogue: lane (d & 7) stores dim d ----
  float uo[LATENT], eo[LATENT], so[LATENT], mo[LATENT];
#pragma unroll
  for (int p = 0; p < 5; ++p) {
    uo[2 * p] = u2[p].x;     uo[2 * p + 1] = u2[p].y;
    eo[2 * p] = errs2[p].x;  eo[2 * p + 1] = errs2[p].y;
    so[2 * p] = shalf2[p].x; so[2 * p + 1] = shalf2[p].y;
    mo[2 * p] = mu2[p].x;    mo[2 * p + 1] = mu2[p].y;
  }
#pragma unroll
  for (int d = 0; d < LATENT; ++d) {
    if ((d & 7) == r) {
      float sd = so[d] + so[d];                       // == sstd exactly
      outSeq[base + d] = fmaf(sd, uo[d], mo[d]);
      outErr[base + d] = eo[d];
    }
  }
}

// ---------------------------------------------------------------------------
// Fallback (ws too small): known-correct mono kernel.
// ---------------------------------------------------------------------------
__global__ __launch_bounds__(64) void k_mono(
    const float* __restrict__ zmean, const float* __restrict__ zlv,
    const float* __restrict__ W1, const float* __restrict__ b1v,
    const float* __restrict__ W2, const float* __restrict__ b2v,
    float* __restrict__ outSeq, float* __restrict__ outErr) {
  int i = blockIdx.x >> 3;
  int b = ((blockIdx.x & 7) << 6) + threadIdx.x;
  float pref[HIDDEN];
#pragma unroll
  for (int j = 0; j < HIDDEN; ++j) pref[j] = 0.0f;
  for (int l = 0; l < i; ++l) {
    const float* mrow = zmean + (b * MAXLEN + l) * LATENT;
    const float* wrow = W1 + (l * LATENT) * HIDDEN;
#pragma unroll
    for (int d = 0; d < LATENT; ++d) {
      float m = mrow[d];
#pragma unroll
      for (int j = 0; j < HIDDEN; ++j) pref[j] = fmaf(m, wrow[d * HIDDEN + j], pref[j]);
    }
  }
  const int base = (b * MAXLEN + i) * LATENT;
  float mu[LATENT], sstd[LATENT], xt[LATENT], errs[LATENT];
#pragma unroll
  for (int d = 0; d < LATENT; ++d) {
    mu[d] = zmean[base + d];
    sstd[d] = sqrtf(expf(zlv[base + d]));
  }
  float n0[LATENT];
  {
    uint32_t a, c;
    tf2x32(0u, 1337u, 0u, (uint32_t)(i * (STEPS + 1)), a, c);
#pragma unroll
    for (int d = 0; d < LATENT; ++d) {
      uint32_t o0, o1;
      tf2x32(a, c, 0u, (uint32_t)(b * LATENT + d), o0, o1);
      n0[d] = bits_to_normal(o0 ^ o1);
    }
  }
#pragma unroll
  for (int d = 0; d < LATENT; ++d) { xt[d] = mu[d] + sstd[d] * n0[d]; errs[d] = 0.0f; }
  const float* rowT  = W1 + (MAXLEN * LATENT) * HIDDEN;
  const float* rowsI = W1 + (i * LATENT) * HIDDEN;
  const float SQRT_DT = 0.31622776601683794f;
  for (int s = 0; s < STEPS; ++s) {
    float t = (float)i + (float)s * 0.1f;
    float h[HIDDEN];
#pragma unroll
    for (int j = 0; j < HIDDEN; ++j) h[j] = pref[j];
#pragma unroll
    for (int d = 0; d < LATENT; ++d) {
      float xd = xt[d];
      const float* row = rowsI + d * HIDDEN;
#pragma unroll
      for (int j = 0; j < HIDDEN; ++j) h[j] = fmaf(xd, row[j], h[j]);
    }
    float sc[LATENT];
#pragma unroll
    for (int d = 0; d < LATENT; ++d) sc[d] = b2v[d];
#pragma unroll
    for (int j = 0; j < HIDDEN; ++j) {
      float hj = fmaf(t, rowT[j], h[j]) + b1v[j];
      hj = fmaxf(hj, 0.0f);
      const float* w2r = W2 + j * LATENT;
#pragma unroll
      for (int d = 0; d < LATENT; ++d) sc[d] = fmaf(hj, w2r[d], sc[d]);
    }
    float nd[LATENT];
    {
      uint32_t a, c;
      tf2x32(0u, 1337u, 0u, (uint32_t)(i * (STEPS + 1) + s + 1), a, c);
#pragma unroll
      for (int d = 0; d < LATENT; ++d) {
        uint32_t o0, o1;
        tf2x32(a, c, 0u, (uint32_t)(b * LATENT + d), o0, o1);
        nd[d] = bits_to_normal(o0 ^ o1);
      }
    }
#pragma unroll
    for (int d = 0; d < LATENT; ++d) {
      float logdx = -(xt[d] - mu[d]) / sstd[d];
      errs[d] += fabsf(logdx - sc[d]);
      float dW = nd[d] * SQRT_DT;
      xt[d] = xt[d] + (0.5f * (sstd[d] * sstd[d])) * sc[d] + sstd[d] * dW;
    }
  }
#pragma unroll
  for (int d = 0; d < LATENT; ++d) {
    outSeq[base + d] = xt[d];
    outErr[base + d] = errs[d];
  }
}

// ---------------------------------------------------------------------------
extern "C" void kernel_launch(void* const* d_in, const int* in_sizes, int n_in,
                              void* d_out, int out_size, void* d_ws, size_t ws_size,
                              hipStream_t stream) {
  (void)in_sizes; (void)n_in; (void)out_size;
  const float* zmean = (const float*)d_in[0];
  const float* zlv   = (const float*)d_in[1];
  const float* W1    = (const float*)d_in[2];
  const float* b1v   = (const float*)d_in[3];
  const float* W2    = (const float*)d_in[4];
  const float* b2v   = (const float*)d_in[5];
  float* outSeq = (float*)d_out;
  float* outErr = outSeq + (size_t)BATCH * MAXLEN * LATENT;

  const size_t segBytes = (size_t)NSEG * BATCH * HIDDEN * sizeof(float);   // 1,048,576

  if (ws_size >= segBytes) {
    float* segtot = (float*)d_ws;
    hipLaunchKernelGGL(k_seg, dim3(NSEG * BATCH * HIDDEN / 256), dim3(256), 0, stream,
                       zmean, W1, segtot);
    hipLaunchKernelGGL(k_chain, dim3(MAXLEN * (BATCH / CPB)), dim3(TPB), 0, stream,
                       zmean, zlv, W1, b1v, W2, b2v, segtot, outSeq, outErr);
  } else {
    hipLaunchKernelGGL(k_mono, dim3(MAXLEN * 8), dim3(64), 0, stream,
                       zmean, zlv, W1, b1v, W2, b2v, outSeq, outErr);
  }
}

// Round 14
// 105.356 us; speedup vs baseline: 1.2646x; 1.2646x over previous
//
#include <hip/hip_runtime.h>
#include <stdint.h>

#define LATENT 10
#define MAXLEN 80
#define STEPS  10
#define HIDDEN 32
#define BATCH  512
#define NSEG   16
#define SEGL   5       // MAXLEN / NSEG
#define CPB    16      // chains per block
#define TPB    128     // threads per block (2 waves, all productive)

// ---------------------------------------------------------------------------
// Threefry-2x32, 20 rounds — bit-exact replica of jax threefry2x32_p.
// ---------------------------------------------------------------------------
__device__ __forceinline__ void tf2x32(uint32_t k0, uint32_t k1,
                                       uint32_t x0, uint32_t x1,
                                       uint32_t& o0, uint32_t& o1) {
  uint32_t ks2 = k0 ^ k1 ^ 0x1BD11BDAu;
  uint32_t v0 = x0 + k0;
  uint32_t v1 = x1 + k1;
#define TF_R(rot) { v0 += v1; v1 = (v1 << (rot)) | (v1 >> (32 - (rot))); v1 ^= v0; }
  TF_R(13) TF_R(15) TF_R(26) TF_R(6)
  v0 += k1;  v1 += ks2 + 1u;
  TF_R(17) TF_R(29) TF_R(16) TF_R(24)
  v0 += ks2; v1 += k0 + 2u;
  TF_R(13) TF_R(15) TF_R(26) TF_R(6)
  v0 += k0;  v1 += k1 + 3u;
  TF_R(17) TF_R(29) TF_R(16) TF_R(24)
  v0 += k1;  v1 += ks2 + 4u;
  TF_R(13) TF_R(15) TF_R(26) TF_R(6)
  v0 += ks2; v1 += k0 + 5u;
#undef TF_R
  o0 = v0; o1 = v1;
}

// JAX uniform(-0.99999994, 1) bits -> sqrt(2)*erfinv(u).
// XLA Giles polynomial; w via fast hw log (1-ulp class, threshold has 10x margin).
__device__ __forceinline__ float bits_to_normal(uint32_t bits) {
  const float lo = -0.99999994f;                                 // nextafter(-1, 0)
  float f = __uint_as_float((bits >> 9) | 0x3f800000u) - 1.0f;   // [0,1)
  float u = fmaf(f, 2.0f, lo);                                   // (hi-lo) rounds to 2.0f
  u = fmaxf(u, lo);
  float w = -__logf(fmaf(-u, u, 1.0f));                          // -ln(1-u^2)
  float p;
  if (w < 5.0f) {
    w -= 2.5f;
    p = 2.81022636e-08f;
    p = fmaf(p, w, 3.43273939e-07f);
    p = fmaf(p, w, -3.5233877e-06f);
    p = fmaf(p, w, -4.39150654e-06f);
    p = fmaf(p, w, 0.00021858087f);
    p = fmaf(p, w, -0.00125372503f);
    p = fmaf(p, w, -0.00417768164f);
    p = fmaf(p, w, 0.246640727f);
    p = fmaf(p, w, 1.50140941f);
  } else {
    w = sqrtf(w) - 3.0f;
    p = -0.000200214257f;
    p = fmaf(p, w, 0.000100950558f);
    p = fmaf(p, w, 0.00134934322f);
    p = fmaf(p, w, -0.00367342844f);
    p = fmaf(p, w, 0.00573950773f);
    p = fmaf(p, w, -0.0076224613f);
    p = fmaf(p, w, 0.00943887047f);
    p = fmaf(p, w, 1.00167406f);
    p = fmaf(p, w, 2.83297682f);
  }
  return 1.4142135623730951f * (p * u);
}

// ---------------------------------------------------------------------------
// Kernel 1: segment totals.
// segtot[s][b][j] = sum_{l in [5s,5s+5)} mu[b,l,:] . W1[l*10:l*10+10, j]
// ---------------------------------------------------------------------------
__global__ __launch_bounds__(256) void k_seg(
    const float* __restrict__ zmean, const float* __restrict__ W1,
    float* __restrict__ segtot) {
  int id = blockIdx.x * 256 + threadIdx.x;    // 0..262143
  int s = id >> 14;                           // segment, block-uniform
  int r = id & 16383;
  int b = r >> 5, j = r & 31;
  float pf0 = 0.0f, pf1 = 0.0f;
#pragma unroll
  for (int t = 0; t < SEGL; ++t) {
    int l = s * SEGL + t;
    const float2* mrow = (const float2*)(zmean + (b * MAXLEN + l) * LATENT);
    float2 m0 = mrow[0], m1 = mrow[1], m2 = mrow[2], m3 = mrow[3], m4 = mrow[4];
    const float* wl = W1 + (l * LATENT) * HIDDEN + j;
    pf0 = fmaf(m0.x, wl[0 * HIDDEN], pf0);
    pf1 = fmaf(m0.y, wl[1 * HIDDEN], pf1);
    pf0 = fmaf(m1.x, wl[2 * HIDDEN], pf0);
    pf1 = fmaf(m1.y, wl[3 * HIDDEN], pf1);
    pf0 = fmaf(m2.x, wl[4 * HIDDEN], pf0);
    pf1 = fmaf(m2.y, wl[5 * HIDDEN], pf1);
    pf0 = fmaf(m3.x, wl[6 * HIDDEN], pf0);
    pf1 = fmaf(m3.y, wl[7 * HIDDEN], pf1);
    pf0 = fmaf(m4.x, wl[8 * HIDDEN], pf0);
    pf1 = fmaf(m4.y, wl[9 * HIDDEN], pf1);
  }
  segtot[(s * BATCH + b) * HIDDEN + j] = pf0 + pf1;
}

// ---------------------------------------------------------------------------
// Kernel 2: block = (i, 16 b's), 128 threads (2 waves), 2560 blocks — whole
// grid co-resident at the natural VGPR footprint (84).
// VGPR law (measured): 84 is the operating point. R11 (cap to 40) -> 500 MB
// spill, 3.7x slower. R13 (packed v2f, 136) -> occupancy halved, 1.6x slower.
// Do NOT add min-waves hints and do NOT use ext_vector_type state here.
// Phase A: 11 subkeys -> LDS. Phase B: 1760 normals -> LDS (13 full rounds +
// 96-thread tail), dW draws pre-scaled by sqrt(dt). Phase C: 8 lanes/chain,
// lane r owns hidden units [4r,4r+4); normalized state u=(xt-mu)/sstd;
// mu and sstd folded into per-lane register weights.
// ---------------------------------------------------------------------------
__global__ __launch_bounds__(TPB) void k_chain(
    const float* __restrict__ zmean, const float* __restrict__ zlv,
    const float* __restrict__ W1, const float* __restrict__ b1v,
    const float* __restrict__ W2, const float* __restrict__ b2v,
    const float* __restrict__ segtot,
    float* __restrict__ outSeq, float* __restrict__ outErr) {
  __shared__ float nrmS[(STEPS + 1) * LATENT * CPB];  // 7040 B
  __shared__ uint32_t skk[2 * (STEPS + 1)];

  const int tid = threadIdx.x;
  const int i = blockIdx.x >> 5;                      // block-uniform
  const int b0 = (blockIdx.x & 31) << 4;

  // ---- phase A: 11 subkeys for this i ----
  if (tid < (STEPS + 1)) {
    uint32_t a, c;
    tf2x32(0u, 1337u, 0u, (uint32_t)(i * (STEPS + 1) + tid), a, c);
    skk[2 * tid] = a; skk[2 * tid + 1] = c;
  }
  __syncthreads();

  // ---- phase B: 1760 normals (13 full rounds + 96-thread tail) ----
  const float SQRT_DT = 0.31622776601683794f;
#define GEN_DRAW(IDX)                                                        \
  {                                                                          \
    int c_ = (IDX) & (CPB - 1), n_ = (IDX) >> 4;                             \
    int k_ = (n_ * 205) >> 11;                                               \
    int d_ = n_ - k_ * 10;                                                   \
    uint32_t o0_, o1_;                                                       \
    tf2x32(skk[2 * k_], skk[2 * k_ + 1], 0u,                                 \
           (uint32_t)((b0 + c_) * LATENT + d_), o0_, o1_);                   \
    float v_ = bits_to_normal(o0_ ^ o1_);                                    \
    nrmS[n_ * CPB + c_] = (n_ < LATENT) ? v_ : v_ * SQRT_DT;                 \
  }
#pragma unroll
  for (int rr = 0; rr < 13; ++rr) GEN_DRAW(rr * TPB + tid);
  if (tid < (STEPS + 1) * LATENT * CPB - 13 * TPB) GEN_DRAW(13 * TPB + tid);
#undef GEN_DRAW
  __syncthreads();

  // ---- phase C: all 128 threads = 16 chains x 8 lanes ----
  const int r = tid & 7;                              // lane-in-chain
  const int jb = r * 4;                               // first hidden unit
  const int cloc = tid >> 3;                          // chain-in-block
  const int b = b0 + cloc;

  // base hidden pre-activation: pf = b1 + i*wT + prefix(segments + partials)
  const float* rowT = W1 + (MAXLEN * LATENT) * HIDDEN;
  float pf[4], wT[4];
  const float fi = (float)i;
#pragma unroll
  for (int k = 0; k < 4; ++k) {
    wT[k] = rowT[jb + k];
    pf[k] = fmaf(fi, wT[k], b1v[jb + k]);
  }
  const int fs = i / SEGL;                            // full segments (uniform)
  for (int s2 = 0; s2 < fs; ++s2) {
    float4 t0 = *(const float4*)(segtot + ((size_t)s2 * BATCH + b) * HIDDEN + jb);
    pf[0] += t0.x; pf[1] += t0.y; pf[2] += t0.z; pf[3] += t0.w;
  }
  for (int l = fs * SEGL; l < i; ++l) {               // <= 4 partial l's
    const float2* mrow = (const float2*)(zmean + (b * MAXLEN + l) * LATENT);
    const float* wl = W1 + (l * LATENT) * HIDDEN + jb;
#pragma unroll
    for (int p = 0; p < 5; ++p) {
      float2 m = mrow[p];
      float4 wa = *(const float4*)(wl + (2 * p) * HIDDEN);
      float4 wb = *(const float4*)(wl + (2 * p + 1) * HIDDEN);
      pf[0] = fmaf(m.x, wa.x, pf[0]); pf[1] = fmaf(m.x, wa.y, pf[1]);
      pf[2] = fmaf(m.x, wa.z, pf[2]); pf[3] = fmaf(m.x, wa.w, pf[3]);
      pf[0] = fmaf(m.y, wb.x, pf[0]); pf[1] = fmaf(m.y, wb.y, pf[1]);
      pf[2] = fmaf(m.y, wb.z, pf[2]); pf[3] = fmaf(m.y, wb.w, pf[3]);
    }
  }

  // per-chain latent params; fold mu into pf, sstd into W1 lane slice
  const int base = (b * MAXLEN + i) * LATENT;
  float mu[LATENT], shalf[LATENT], u[LATENT], errs[LATENT], b2[LATENT];
  float w1s[LATENT][4];
  {
    const float2* zm = (const float2*)(zmean + base);
    const float2* zl = (const float2*)(zlv + base);
    const float* W1i = W1 + (i * LATENT) * HIDDEN + jb;
#pragma unroll
    for (int p = 0; p < 5; ++p) {
      float2 m = zm[p], v = zl[p];
      float s0 = sqrtf(expf(v.x));
      float s1 = sqrtf(expf(v.y));
      mu[2 * p] = m.x; mu[2 * p + 1] = m.y;
      shalf[2 * p] = 0.5f * s0; shalf[2 * p + 1] = 0.5f * s1;
      float4 wa = *(const float4*)(W1i + (2 * p) * HIDDEN);
      float4 wb = *(const float4*)(W1i + (2 * p + 1) * HIDDEN);
      // pf += mu_d * w1_d  (step-invariant part of xt = mu + sstd*u)
      pf[0] = fmaf(m.x, wa.x, pf[0]); pf[1] = fmaf(m.x, wa.y, pf[1]);
      pf[2] = fmaf(m.x, wa.z, pf[2]); pf[3] = fmaf(m.x, wa.w, pf[3]);
      pf[0] = fmaf(m.y, wb.x, pf[0]); pf[1] = fmaf(m.y, wb.y, pf[1]);
      pf[2] = fmaf(m.y, wb.z, pf[2]); pf[3] = fmaf(m.y, wb.w, pf[3]);
      // scaled weights: w1s[d][k] = sstd_d * w1[d][k]
      w1s[2 * p][0] = s0 * wa.x; w1s[2 * p][1] = s0 * wa.y;
      w1s[2 * p][2] = s0 * wa.z; w1s[2 * p][3] = s0 * wa.w;
      w1s[2 * p + 1][0] = s1 * wb.x; w1s[2 * p + 1][1] = s1 * wb.y;
      w1s[2 * p + 1][2] = s1 * wb.z; w1s[2 * p + 1][3] = s1 * wb.w;
    }
  }
#pragma unroll
  for (int d = 0; d < LATENT; ++d) {
    b2[d] = b2v[d];
    errs[d] = 0.0f;
    u[d] = nrmS[d * CPB + cloc];                      // k = 0 draw: u0 = n0
  }

  const float* W2q = W2 + jb * LATENT;

  for (int s = 0; s < STEPS; ++s) {
    // this step's noise (k = s+1), pre-scaled by sqrt(dt); bank-broadcast reads
    float nd[LATENT];
#pragma unroll
    for (int d = 0; d < LATENT; ++d)
      nd[d] = nrmS[((s + 1) * LATENT + d) * CPB + cloc];

    const float ts = (float)s * 0.1f;
    float h[4];
#pragma unroll
    for (int k = 0; k < 4; ++k) h[k] = fmaf(ts, wT[k], pf[k]);
#pragma unroll
    for (int d = 0; d < LATENT; ++d) {
      const float ud = u[d];
      h[0] = fmaf(ud, w1s[d][0], h[0]); h[1] = fmaf(ud, w1s[d][1], h[1]);
      h[2] = fmaf(ud, w1s[d][2], h[2]); h[3] = fmaf(ud, w1s[d][3], h[3]);
    }
    // partial score over this lane's 4 hidden units
    float sc[LATENT];
#pragma unroll
    for (int d = 0; d < LATENT; ++d) sc[d] = 0.0f;
#pragma unroll
    for (int k = 0; k < 4; ++k) {
      const float hj = fmaxf(h[k], 0.0f);
      const float2* w2r = (const float2*)(W2q + k * LATENT);
#pragma unroll
      for (int p = 0; p < 5; ++p) {
        float2 w = w2r[p];
        sc[2 * p] = fmaf(hj, w.x, sc[2 * p]);
        sc[2 * p + 1] = fmaf(hj, w.y, sc[2 * p + 1]);
      }
    }
    // reduce across the 8 lanes of the chain
#pragma unroll
    for (int m = 1; m < 8; m <<= 1) {
#pragma unroll
      for (int d = 0; d < LATENT; ++d) sc[d] += __shfl_xor(sc[d], m);
    }
    // update: u += shalf*st + nd ; err += |u + st|
#pragma unroll
    for (int d = 0; d < LATENT; ++d) {
      float st = sc[d] + b2[d];
      errs[d] += fabsf(u[d] + st);                    // |logdx - st|, logdx = -u
      u[d] = u[d] + fmaf(shalf[d], st, nd[d]);
    }
  }

  // ---- epilogue: lane (d & 7) stores dim d ----
#pragma unroll
  for (int d = 0; d < LATENT; ++d) {
    if ((d & 7) == r) {
      float sd = shalf[d] + shalf[d];                 // == sstd exactly
      outSeq[base + d] = fmaf(sd, u[d], mu[d]);
      outErr[base + d] = errs[d];
    }
  }
}

// ---------------------------------------------------------------------------
// Fallback (ws too small): known-correct mono kernel.
// ---------------------------------------------------------------------------
__global__ __launch_bounds__(64) void k_mono(
    const float* __restrict__ zmean, const float* __restrict__ zlv,
    const float* __restrict__ W1, const float* __restrict__ b1v,
    const float* __restrict__ W2, const float* __restrict__ b2v,
    float* __restrict__ outSeq, float* __restrict__ outErr) {
  int i = blockIdx.x >> 3;
  int b = ((blockIdx.x & 7) << 6) + threadIdx.x;
  float pref[HIDDEN];
#pragma unroll
  for (int j = 0; j < HIDDEN; ++j) pref[j] = 0.0f;
  for (int l = 0; l < i; ++l) {
    const float* mrow = zmean + (b * MAXLEN + l) * LATENT;
    const float* wrow = W1 + (l * LATENT) * HIDDEN;
#pragma unroll
    for (int d = 0; d < LATENT; ++d) {
      float m = mrow[d];
#pragma unroll
      for (int j = 0; j < HIDDEN; ++j) pref[j] = fmaf(m, wrow[d * HIDDEN + j], pref[j]);
    }
  }
  const int base = (b * MAXLEN + i) * LATENT;
  float mu[LATENT], sstd[LATENT], xt[LATENT], errs[LATENT];
#pragma unroll
  for (int d = 0; d < LATENT; ++d) {
    mu[d] = zmean[base + d];
    sstd[d] = sqrtf(expf(zlv[base + d]));
  }
  float n0[LATENT];
  {
    uint32_t a, c;
    tf2x32(0u, 1337u, 0u, (uint32_t)(i * (STEPS + 1)), a, c);
#pragma unroll
    for (int d = 0; d < LATENT; ++d) {
      uint32_t o0, o1;
      tf2x32(a, c, 0u, (uint32_t)(b * LATENT + d), o0, o1);
      n0[d] = bits_to_normal(o0 ^ o1);
    }
  }
#pragma unroll
  for (int d = 0; d < LATENT; ++d) { xt[d] = mu[d] + sstd[d] * n0[d]; errs[d] = 0.0f; }
  const float* rowT  = W1 + (MAXLEN * LATENT) * HIDDEN;
  const float* rowsI = W1 + (i * LATENT) * HIDDEN;
  const float SQRT_DT = 0.31622776601683794f;
  for (int s = 0; s < STEPS; ++s) {
    float t = (float)i + (float)s * 0.1f;
    float h[HIDDEN];
#pragma unroll
    for (int j = 0; j < HIDDEN; ++j) h[j] = pref[j];
#pragma unroll
    for (int d = 0; d < LATENT; ++d) {
      float xd = xt[d];
      const float* row = rowsI + d * HIDDEN;
#pragma unroll
      for (int j = 0; j < HIDDEN; ++j) h[j] = fmaf(xd, row[j], h[j]);
    }
    float sc[LATENT];
#pragma unroll
    for (int d = 0; d < LATENT; ++d) sc[d] = b2v[d];
#pragma unroll
    for (int j = 0; j < HIDDEN; ++j) {
      float hj = fmaf(t, rowT[j], h[j]) + b1v[j];
      hj = fmaxf(hj, 0.0f);
      const float* w2r = W2 + j * LATENT;
#pragma unroll
      for (int d = 0; d < LATENT; ++d) sc[d] = fmaf(hj, w2r[d], sc[d]);
    }
    float nd[LATENT];
    {
      uint32_t a, c;
      tf2x32(0u, 1337u, 0u, (uint32_t)(i * (STEPS + 1) + s + 1), a, c);
#pragma unroll
      for (int d = 0; d < LATENT; ++d) {
        uint32_t o0, o1;
        tf2x32(a, c, 0u, (uint32_t)(b * LATENT + d), o0, o1);
        nd[d] = bits_to_normal(o0 ^ o1);
      }
    }
#pragma unroll
    for (int d = 0; d < LATENT; ++d) {
      float logdx = -(xt[d] - mu[d]) / sstd[d];
      errs[d] += fabsf(logdx - sc[d]);
      float dW = nd[d] * SQRT_DT;
      xt[d] = xt[d] + (0.5f * (sstd[d] * sstd[d])) * sc[d] + sstd[d] * dW;
    }
  }
#pragma unroll
  for (int d = 0; d < LATENT; ++d) {
    outSeq[base + d] = xt[d];
    outErr[base + d] = errs[d];
  }
}

// ---------------------------------------------------------------------------
extern "C" void kernel_launch(void* const* d_in, const int* in_sizes, int n_in,
                              void* d_out, int out_size, void* d_ws, size_t ws_size,
                              hipStream_t stream) {
  (void)in_sizes; (void)n_in; (void)out_size;
  const float* zmean = (const float*)d_in[0];
  const float* zlv   = (const float*)d_in[1];
  const float* W1    = (const float*)d_in[2];
  const float* b1v   = (const float*)d_in[3];
  const float* W2    = (const float*)d_in[4];
  const float* b2v   = (const float*)d_in[5];
  float* outSeq = (float*)d_out;
  float* outErr = outSeq + (size_t)BATCH * MAXLEN * LATENT;

  const size_t segBytes = (size_t)NSEG * BATCH * HIDDEN * sizeof(float);   // 1,048,576

  if (ws_size >= segBytes) {
    float* segtot = (float*)d_ws;
    hipLaunchKernelGGL(k_seg, dim3(NSEG * BATCH * HIDDEN / 256), dim3(256), 0, stream,
                       zmean, W1, segtot);
    hipLaunchKernelGGL(k_chain, dim3(MAXLEN * (BATCH / CPB)), dim3(TPB), 0, stream,
                       zmean, zlv, W1, b1v, W2, b2v, segtot, outSeq, outErr);
  } else {
    hipLaunchKernelGGL(k_mono, dim3(MAXLEN * 8), dim3(64), 0, stream,
                       zmean, zlv, W1, b1v, W2, b2v, outSeq, outErr);
  }
}

// Round 16
// 104.889 us; speedup vs baseline: 1.2703x; 1.0045x over previous
//
#include <hip/hip_runtime.h>
#include <stdint.h>

#define LATENT 10
#define MAXLEN 80
#define STEPS  10
#define HIDDEN 32
#define BATCH  512
#define NSEG   16
#define SEGL   5       // MAXLEN / NSEG
#define CPB    16      // chains per block
#define TPB    128     // threads per block (2 waves, all productive)

// ---------------------------------------------------------------------------
// Threefry-2x32, 20 rounds — bit-exact replica of jax threefry2x32_p.
// ---------------------------------------------------------------------------
__device__ __forceinline__ void tf2x32(uint32_t k0, uint32_t k1,
                                       uint32_t x0, uint32_t x1,
                                       uint32_t& o0, uint32_t& o1) {
  uint32_t ks2 = k0 ^ k1 ^ 0x1BD11BDAu;
  uint32_t v0 = x0 + k0;
  uint32_t v1 = x1 + k1;
#define TF_R(rot) { v0 += v1; v1 = (v1 << (rot)) | (v1 >> (32 - (rot))); v1 ^= v0; }
  TF_R(13) TF_R(15) TF_R(26) TF_R(6)
  v0 += k1;  v1 += ks2 + 1u;
  TF_R(17) TF_R(29) TF_R(16) TF_R(24)
  v0 += ks2; v1 += k0 + 2u;
  TF_R(13) TF_R(15) TF_R(26) TF_R(6)
  v0 += k0;  v1 += k1 + 3u;
  TF_R(17) TF_R(29) TF_R(16) TF_R(24)
  v0 += k1;  v1 += ks2 + 4u;
  TF_R(13) TF_R(15) TF_R(26) TF_R(6)
  v0 += ks2; v1 += k0 + 5u;
#undef TF_R
  o0 = v0; o1 = v1;
}

// JAX uniform(-0.99999994, 1) bits -> sqrt(2)*erfinv(u).
// XLA Giles polynomial; w via fast hw log (1-ulp class, threshold has 10x margin).
__device__ __forceinline__ float bits_to_normal(uint32_t bits) {
  const float lo = -0.99999994f;                                 // nextafter(-1, 0)
  float f = __uint_as_float((bits >> 9) | 0x3f800000u) - 1.0f;   // [0,1)
  float u = fmaf(f, 2.0f, lo);                                   // (hi-lo) rounds to 2.0f
  u = fmaxf(u, lo);
  float w = -__logf(fmaf(-u, u, 1.0f));                          // -ln(1-u^2)
  float p;
  if (w < 5.0f) {
    w -= 2.5f;
    p = 2.81022636e-08f;
    p = fmaf(p, w, 3.43273939e-07f);
    p = fmaf(p, w, -3.5233877e-06f);
    p = fmaf(p, w, -4.39150654e-06f);
    p = fmaf(p, w, 0.00021858087f);
    p = fmaf(p, w, -0.00125372503f);
    p = fmaf(p, w, -0.00417768164f);
    p = fmaf(p, w, 0.246640727f);
    p = fmaf(p, w, 1.50140941f);
  } else {
    w = sqrtf(w) - 3.0f;
    p = -0.000200214257f;
    p = fmaf(p, w, 0.000100950558f);
    p = fmaf(p, w, 0.00134934322f);
    p = fmaf(p, w, -0.00367342844f);
    p = fmaf(p, w, 0.00573950773f);
    p = fmaf(p, w, -0.0076224613f);
    p = fmaf(p, w, 0.00943887047f);
    p = fmaf(p, w, 1.00167406f);
    p = fmaf(p, w, 2.83297682f);
  }
  return 1.4142135623730951f * (p * u);
}

// ---------------------------------------------------------------------------
// Kernel 1: segment totals.
// segtot[s][b][j] = sum_{l in [5s,5s+5)} mu[b,l,:] . W1[l*10:l*10+10, j]
// ---------------------------------------------------------------------------
__global__ __launch_bounds__(256) void k_seg(
    const float* __restrict__ zmean, const float* __restrict__ W1,
    float* __restrict__ segtot) {
  int id = blockIdx.x * 256 + threadIdx.x;    // 0..262143
  int s = id >> 14;                           // segment, block-uniform
  int r = id & 16383;
  int b = r >> 5, j = r & 31;
  float pf0 = 0.0f, pf1 = 0.0f;
#pragma unroll
  for (int t = 0; t < SEGL; ++t) {
    int l = s * SEGL + t;
    const float2* mrow = (const float2*)(zmean + (b * MAXLEN + l) * LATENT);
    float2 m0 = mrow[0], m1 = mrow[1], m2 = mrow[2], m3 = mrow[3], m4 = mrow[4];
    const float* wl = W1 + (l * LATENT) * HIDDEN + j;
    pf0 = fmaf(m0.x, wl[0 * HIDDEN], pf0);
    pf1 = fmaf(m0.y, wl[1 * HIDDEN], pf1);
    pf0 = fmaf(m1.x, wl[2 * HIDDEN], pf0);
    pf1 = fmaf(m1.y, wl[3 * HIDDEN], pf1);
    pf0 = fmaf(m2.x, wl[4 * HIDDEN], pf0);
    pf1 = fmaf(m2.y, wl[5 * HIDDEN], pf1);
    pf0 = fmaf(m3.x, wl[6 * HIDDEN], pf0);
    pf1 = fmaf(m3.y, wl[7 * HIDDEN], pf1);
    pf0 = fmaf(m4.x, wl[8 * HIDDEN], pf0);
    pf1 = fmaf(m4.y, wl[9 * HIDDEN], pf1);
  }
  segtot[(s * BATCH + b) * HIDDEN + j] = pf0 + pf1;
}

// ---------------------------------------------------------------------------
// Kernel 2: block = (i, 16 b's), 128 threads (2 waves), 2560 blocks — whole
// grid co-resident at the natural VGPR footprint (84).
// VGPR law (measured): 84 is the operating point. R11 (cap to 40) -> 500 MB
// spill, 3.7x slower. R13 (packed v2f, 136) -> occupancy halved, 1.6x slower.
// R15: hipLaunchCooperativeKernel breaks the harness's graph capture — the
// two-kernel path is the terminal structure.
// Phase A: 11 subkeys -> LDS. Phase B: 1760 normals -> LDS (13 full rounds +
// 96-thread tail), dW draws pre-scaled by sqrt(dt). Phase C: 8 lanes/chain,
// lane r owns hidden units [4r,4r+4); normalized state u=(xt-mu)/sstd;
// mu and sstd folded into per-lane register weights.
// ---------------------------------------------------------------------------
__global__ __launch_bounds__(TPB) void k_chain(
    const float* __restrict__ zmean, const float* __restrict__ zlv,
    const float* __restrict__ W1, const float* __restrict__ b1v,
    const float* __restrict__ W2, const float* __restrict__ b2v,
    const float* __restrict__ segtot,
    float* __restrict__ outSeq, float* __restrict__ outErr) {
  __shared__ float nrmS[(STEPS + 1) * LATENT * CPB];  // 7040 B
  __shared__ uint32_t skk[2 * (STEPS + 1)];

  const int tid = threadIdx.x;
  const int i = blockIdx.x >> 5;                      // block-uniform
  const int b0 = (blockIdx.x & 31) << 4;

  // ---- phase A: 11 subkeys for this i ----
  if (tid < (STEPS + 1)) {
    uint32_t a, c;
    tf2x32(0u, 1337u, 0u, (uint32_t)(i * (STEPS + 1) + tid), a, c);
    skk[2 * tid] = a; skk[2 * tid + 1] = c;
  }
  __syncthreads();

  // ---- phase B: 1760 normals (13 full rounds + 96-thread tail) ----
  const float SQRT_DT = 0.31622776601683794f;
#define GEN_DRAW(IDX)                                                        \
  {                                                                          \
    int c_ = (IDX) & (CPB - 1), n_ = (IDX) >> 4;                             \
    int k_ = (n_ * 205) >> 11;                                               \
    int d_ = n_ - k_ * 10;                                                   \
    uint32_t o0_, o1_;                                                       \
    tf2x32(skk[2 * k_], skk[2 * k_ + 1], 0u,                                 \
           (uint32_t)((b0 + c_) * LATENT + d_), o0_, o1_);                   \
    float v_ = bits_to_normal(o0_ ^ o1_);                                    \
    nrmS[n_ * CPB + c_] = (n_ < LATENT) ? v_ : v_ * SQRT_DT;                 \
  }
#pragma unroll
  for (int rr = 0; rr < 13; ++rr) GEN_DRAW(rr * TPB + tid);
  if (tid < (STEPS + 1) * LATENT * CPB - 13 * TPB) GEN_DRAW(13 * TPB + tid);
#undef GEN_DRAW
  __syncthreads();

  // ---- phase C: all 128 threads = 16 chains x 8 lanes ----
  const int r = tid & 7;                              // lane-in-chain
  const int jb = r * 4;                               // first hidden unit
  const int cloc = tid >> 3;                          // chain-in-block
  const int b = b0 + cloc;

  // base hidden pre-activation: pf = b1 + i*wT + prefix(segments + partials)
  const float* rowT = W1 + (MAXLEN * LATENT) * HIDDEN;
  float pf[4], wT[4];
  const float fi = (float)i;
#pragma unroll
  for (int k = 0; k < 4; ++k) {
    wT[k] = rowT[jb + k];
    pf[k] = fmaf(fi, wT[k], b1v[jb + k]);
  }
  const int fs = i / SEGL;                            // full segments (uniform)
  for (int s2 = 0; s2 < fs; ++s2) {
    float4 t0 = *(const float4*)(segtot + ((size_t)s2 * BATCH + b) * HIDDEN + jb);
    pf[0] += t0.x; pf[1] += t0.y; pf[2] += t0.z; pf[3] += t0.w;
  }
  for (int l = fs * SEGL; l < i; ++l) {               // <= 4 partial l's
    const float2* mrow = (const float2*)(zmean + (b * MAXLEN + l) * LATENT);
    const float* wl = W1 + (l * LATENT) * HIDDEN + jb;
#pragma unroll
    for (int p = 0; p < 5; ++p) {
      float2 m = mrow[p];
      float4 wa = *(const float4*)(wl + (2 * p) * HIDDEN);
      float4 wb = *(const float4*)(wl + (2 * p + 1) * HIDDEN);
      pf[0] = fmaf(m.x, wa.x, pf[0]); pf[1] = fmaf(m.x, wa.y, pf[1]);
      pf[2] = fmaf(m.x, wa.z, pf[2]); pf[3] = fmaf(m.x, wa.w, pf[3]);
      pf[0] = fmaf(m.y, wb.x, pf[0]); pf[1] = fmaf(m.y, wb.y, pf[1]);
      pf[2] = fmaf(m.y, wb.z, pf[2]); pf[3] = fmaf(m.y, wb.w, pf[3]);
    }
  }

  // per-chain latent params; fold mu into pf, sstd into W1 lane slice
  const int base = (b * MAXLEN + i) * LATENT;
  float mu[LATENT], shalf[LATENT], u[LATENT], errs[LATENT], b2[LATENT];
  float w1s[LATENT][4];
  {
    const float2* zm = (const float2*)(zmean + base);
    const float2* zl = (const float2*)(zlv + base);
    const float* W1i = W1 + (i * LATENT) * HIDDEN + jb;
#pragma unroll
    for (int p = 0; p < 5; ++p) {
      float2 m = zm[p], v = zl[p];
      float s0 = sqrtf(expf(v.x));
      float s1 = sqrtf(expf(v.y));
      mu[2 * p] = m.x; mu[2 * p + 1] = m.y;
      shalf[2 * p] = 0.5f * s0; shalf[2 * p + 1] = 0.5f * s1;
      float4 wa = *(const float4*)(W1i + (2 * p) * HIDDEN);
      float4 wb = *(const float4*)(W1i + (2 * p + 1) * HIDDEN);
      // pf += mu_d * w1_d  (step-invariant part of xt = mu + sstd*u)
      pf[0] = fmaf(m.x, wa.x, pf[0]); pf[1] = fmaf(m.x, wa.y, pf[1]);
      pf[2] = fmaf(m.x, wa.z, pf[2]); pf[3] = fmaf(m.x, wa.w, pf[3]);
      pf[0] = fmaf(m.y, wb.x, pf[0]); pf[1] = fmaf(m.y, wb.y, pf[1]);
      pf[2] = fmaf(m.y, wb.z, pf[2]); pf[3] = fmaf(m.y, wb.w, pf[3]);
      // scaled weights: w1s[d][k] = sstd_d * w1[d][k]
      w1s[2 * p][0] = s0 * wa.x; w1s[2 * p][1] = s0 * wa.y;
      w1s[2 * p][2] = s0 * wa.z; w1s[2 * p][3] = s0 * wa.w;
      w1s[2 * p + 1][0] = s1 * wb.x; w1s[2 * p + 1][1] = s1 * wb.y;
      w1s[2 * p + 1][2] = s1 * wb.z; w1s[2 * p + 1][3] = s1 * wb.w;
    }
  }
#pragma unroll
  for (int d = 0; d < LATENT; ++d) {
    b2[d] = b2v[d];
    errs[d] = 0.0f;
    u[d] = nrmS[d * CPB + cloc];                      // k = 0 draw: u0 = n0
  }

  const float* W2q = W2 + jb * LATENT;

  for (int s = 0; s < STEPS; ++s) {
    // this step's noise (k = s+1), pre-scaled by sqrt(dt); bank-broadcast reads
    float nd[LATENT];
#pragma unroll
    for (int d = 0; d < LATENT; ++d)
      nd[d] = nrmS[((s + 1) * LATENT + d) * CPB + cloc];

    const float ts = (float)s * 0.1f;
    float h[4];
#pragma unroll
    for (int k = 0; k < 4; ++k) h[k] = fmaf(ts, wT[k], pf[k]);
#pragma unroll
    for (int d = 0; d < LATENT; ++d) {
      const float ud = u[d];
      h[0] = fmaf(ud, w1s[d][0], h[0]); h[1] = fmaf(ud, w1s[d][1], h[1]);
      h[2] = fmaf(ud, w1s[d][2], h[2]); h[3] = fmaf(ud, w1s[d][3], h[3]);
    }
    // partial score over this lane's 4 hidden units
    float sc[LATENT];
#pragma unroll
    for (int d = 0; d < LATENT; ++d) sc[d] = 0.0f;
#pragma unroll
    for (int k = 0; k < 4; ++k) {
      const float hj = fmaxf(h[k], 0.0f);
      const float2* w2r = (const float2*)(W2q + k * LATENT);
#pragma unroll
      for (int p = 0; p < 5; ++p) {
        float2 w = w2r[p];
        sc[2 * p] = fmaf(hj, w.x, sc[2 * p]);
        sc[2 * p + 1] = fmaf(hj, w.y, sc[2 * p + 1]);
      }
    }
    // reduce across the 8 lanes of the chain
#pragma unroll
    for (int m = 1; m < 8; m <<= 1) {
#pragma unroll
      for (int d = 0; d < LATENT; ++d) sc[d] += __shfl_xor(sc[d], m);
    }
    // update: u += shalf*st + nd ; err += |u + st|
#pragma unroll
    for (int d = 0; d < LATENT; ++d) {
      float st = sc[d] + b2[d];
      errs[d] += fabsf(u[d] + st);                    // |logdx - st|, logdx = -u
      u[d] = u[d] + fmaf(shalf[d], st, nd[d]);
    }
  }

  // ---- epilogue: lane (d & 7) stores dim d ----
#pragma unroll
  for (int d = 0; d < LATENT; ++d) {
    if ((d & 7) == r) {
      float sd = shalf[d] + shalf[d];                 // == sstd exactly
      outSeq[base + d] = fmaf(sd, u[d], mu[d]);
      outErr[base + d] = errs[d];
    }
  }
}

// ---------------------------------------------------------------------------
// Fallback (ws too small): known-correct mono kernel.
// ---------------------------------------------------------------------------
__global__ __launch_bounds__(64) void k_mono(
    const float* __restrict__ zmean, const float* __restrict__ zlv,
    const float* __restrict__ W1, const float* __restrict__ b1v,
    const float* __restrict__ W2, const float* __restrict__ b2v,
    float* __restrict__ outSeq, float* __restrict__ outErr) {
  int i = blockIdx.x >> 3;
  int b = ((blockIdx.x & 7) << 6) + threadIdx.x;
  float pref[HIDDEN];
#pragma unroll
  for (int j = 0; j < HIDDEN; ++j) pref[j] = 0.0f;
  for (int l = 0; l < i; ++l) {
    const float* mrow = zmean + (b * MAXLEN + l) * LATENT;
    const float* wrow = W1 + (l * LATENT) * HIDDEN;
#pragma unroll
    for (int d = 0; d < LATENT; ++d) {
      float m = mrow[d];
#pragma unroll
      for (int j = 0; j < HIDDEN; ++j) pref[j] = fmaf(m, wrow[d * HIDDEN + j], pref[j]);
    }
  }
  const int base = (b * MAXLEN + i) * LATENT;
  float mu[LATENT], sstd[LATENT], xt[LATENT], errs[LATENT];
#pragma unroll
  for (int d = 0; d < LATENT; ++d) {
    mu[d] = zmean[base + d];
    sstd[d] = sqrtf(expf(zlv[base + d]));
  }
  float n0[LATENT];
  {
    uint32_t a, c;
    tf2x32(0u, 1337u, 0u, (uint32_t)(i * (STEPS + 1)), a, c);
#pragma unroll
    for (int d = 0; d < LATENT; ++d) {
      uint32_t o0, o1;
      tf2x32(a, c, 0u, (uint32_t)(b * LATENT + d), o0, o1);
      n0[d] = bits_to_normal(o0 ^ o1);
    }
  }
#pragma unroll
  for (int d = 0; d < LATENT; ++d) { xt[d] = mu[d] + sstd[d] * n0[d]; errs[d] = 0.0f; }
  const float* rowT  = W1 + (MAXLEN * LATENT) * HIDDEN;
  const float* rowsI = W1 + (i * LATENT) * HIDDEN;
  const float SQRT_DT = 0.31622776601683794f;
  for (int s = 0; s < STEPS; ++s) {
    float t = (float)i + (float)s * 0.1f;
    float h[HIDDEN];
#pragma unroll
    for (int j = 0; j < HIDDEN; ++j) h[j] = pref[j];
#pragma unroll
    for (int d = 0; d < LATENT; ++d) {
      float xd = xt[d];
      const float* row = rowsI + d * HIDDEN;
#pragma unroll
      for (int j = 0; j < HIDDEN; ++j) h[j] = fmaf(xd, row[j], h[j]);
    }
    float sc[LATENT];
#pragma unroll
    for (int d = 0; d < LATENT; ++d) sc[d] = b2v[d];
#pragma unroll
    for (int j = 0; j < HIDDEN; ++j) {
      float hj = fmaf(t, rowT[j], h[j]) + b1v[j];
      hj = fmaxf(hj, 0.0f);
      const float* w2r = W2 + j * LATENT;
#pragma unroll
      for (int d = 0; d < LATENT; ++d) sc[d] = fmaf(hj, w2r[d], sc[d]);
    }
    float nd[LATENT];
    {
      uint32_t a, c;
      tf2x32(0u, 1337u, 0u, (uint32_t)(i * (STEPS + 1) + s + 1), a, c);
#pragma unroll
      for (int d = 0; d < LATENT; ++d) {
        uint32_t o0, o1;
        tf2x32(a, c, 0u, (uint32_t)(b * LATENT + d), o0, o1);
        nd[d] = bits_to_normal(o0 ^ o1);
      }
    }
#pragma unroll
    for (int d = 0; d < LATENT; ++d) {
      float logdx = -(xt[d] - mu[d]) / sstd[d];
      errs[d] += fabsf(logdx - sc[d]);
      float dW = nd[d] * SQRT_DT;
      xt[d] = xt[d] + (0.5f * (sstd[d] * sstd[d])) * sc[d] + sstd[d] * dW;
    }
  }
#pragma unroll
  for (int d = 0; d < LATENT; ++d) {
    outSeq[base + d] = xt[d];
    outErr[base + d] = errs[d];
  }
}

// ---------------------------------------------------------------------------
extern "C" void kernel_launch(void* const* d_in, const int* in_sizes, int n_in,
                              void* d_out, int out_size, void* d_ws, size_t ws_size,
                              hipStream_t stream) {
  (void)in_sizes; (void)n_in; (void)out_size;
  const float* zmean = (const float*)d_in[0];
  const float* zlv   = (const float*)d_in[1];
  const float* W1    = (const float*)d_in[2];
  const float* b1v   = (const float*)d_in[3];
  const float* W2    = (const float*)d_in[4];
  const float* b2v   = (const float*)d_in[5];
  float* outSeq = (float*)d_out;
  float* outErr = outSeq + (size_t)BATCH * MAXLEN * LATENT;

  const size_t segBytes = (size_t)NSEG * BATCH * HIDDEN * sizeof(float);   // 1,048,576

  if (ws_size >= segBytes) {
    float* segtot = (float*)d_ws;
    hipLaunchKernelGGL(k_seg, dim3(NSEG * BATCH * HIDDEN / 256), dim3(256), 0, stream,
                       zmean, W1, segtot);
    hipLaunchKernelGGL(k_chain, dim3(MAXLEN * (BATCH / CPB)), dim3(TPB), 0, stream,
                       zmean, zlv, W1, b1v, W2, b2v, segtot, outSeq, outErr);
  } else {
    hipLaunchKernelGGL(k_mono, dim3(MAXLEN * 8), dim3(64), 0, stream,
                       zmean, zlv, W1, b1v, W2, b2v, outSeq, outErr);
  }
}